// Round 1
// baseline (50.387 us; speedup 1.0000x reference)
//
#include <hip/hip_runtime.h>

// Problem constants
//   B=16, N1=16, TOTAL_IN=1024 (two layers of 512 x dim 8), D1=64
// Key identity: softmax rows sum to 1, so
//   S[b,k,l] = sum_i U[b,k,i,l] * (1 + sum_z bias[k,i,z])
// => never materialize A [16,16,1024,1024] or the softmax.

// ---------------------------------------------------------------------------
// Kernel 1: scale[k*1024+i] = 1 + sum_z bias[k][i][z]   (rows of 1024 f32)
// One wave per row; 4 waves / block.
__global__ __launch_bounds__(256) void bsum_kernel(const float* __restrict__ bias,
                                                   float* __restrict__ scale) {
    int wave = threadIdx.x >> 6;
    int lane = threadIdx.x & 63;
    int row  = blockIdx.x * 4 + wave;                 // [0, 16*1024)
    const float4* rp = (const float4*)(bias + (size_t)row * 1024);
    float s = 0.f;
#pragma unroll
    for (int it = 0; it < 4; ++it) {                  // 4 * 64 lanes * 4 floats = 1024
        float4 v = rp[it * 64 + lane];
        s += v.x + v.y + v.z + v.w;
    }
#pragma unroll
    for (int m = 32; m >= 1; m >>= 1) s += __shfl_xor(s, m);
    if (lane == 0) scale[row] = 1.0f + s;
}

// ---------------------------------------------------------------------------
// Kernel 2: per block: fixed k, a group of 16-row i-chunks.
//   acc[b][l] += sum_{i in chunk} scale[k,i] * sum_j x[b,i,j] * W[k,i,j,l]
// Thread t: b = t>>4 (16 b's), q = t&15 (l-quad, 4 l's) -> float4 acc.
// Writes deterministic partials: partial[blockIdx][b][l].
__global__ __launch_bounds__(256) void proj_kernel(
        const float* __restrict__ x0, const float* __restrict__ x1,
        const float* __restrict__ W0, const float* __restrict__ W1,
        const float* __restrict__ scale, float* __restrict__ partial,
        int cpb, int ncg) {
    __shared__ float xs[16 * 132];   // [i_local][b*8+j], stride 132 avoids bank conflicts
    const int tid = threadIdx.x;
    const int k    = blockIdx.x / ncg;
    const int cgrp = blockIdx.x % ncg;
    const int b = tid >> 4;          // [0,16)
    const int q = tid & 15;          // l-quad [0,16)

    float4 acc = make_float4(0.f, 0.f, 0.f, 0.f);

    for (int cc = 0; cc < cpb; ++cc) {
        const int chunk = cgrp * cpb + cc;        // [0,64)
        const int layer = chunk >> 5;             // 0: first 512 caps, 1: second
        const int i0    = (chunk & 31) * 16;      // i within layer [0,512)
        const int ig0   = chunk * 16;             // global i [0,1024)
        const float* __restrict__ x = layer ? x1 : x0;
        const float* __restrict__ W = layer ? W1 : W0;

        __syncthreads();   // protect LDS reuse across chunks
        {
            // stage xs[il][bb][j] = x[bb, i0+il, j] * scale[k, ig0+il]
            const int il = tid & 15, bb = tid >> 4;
            const float s = scale[k * 1024 + ig0 + il];
            const float4* xp = (const float4*)(x + (size_t)(bb * 512 + i0 + il) * 8);
            float4 a0 = xp[0], a1 = xp[1];
            float4* dst = (float4*)&xs[il * 132 + bb * 8];
            dst[0] = make_float4(a0.x * s, a0.y * s, a0.z * s, a0.w * s);
            dst[1] = make_float4(a1.x * s, a1.y * s, a1.z * s, a1.w * s);
        }
        __syncthreads();

        const float4* Wf4 = (const float4*)W;
        // float4 index of W[k][i0+il][j][q*4]: (k*512+i0+il)*128 + j*16 + q
        const size_t base = (size_t)(k * 512 + i0) * 128 + q;
        for (int il = 0; il < 16; ++il) {
            float xr[8];
            *(float4*)&xr[0] = *(const float4*)&xs[il * 132 + b * 8];
            *(float4*)&xr[4] = *(const float4*)&xs[il * 132 + b * 8 + 4];
            const float4* wp = Wf4 + base + (size_t)il * 128;
#pragma unroll
            for (int j = 0; j < 8; ++j) {
                float4 w = wp[j * 16];
                acc.x += xr[j] * w.x;
                acc.y += xr[j] * w.y;
                acc.z += xr[j] * w.z;
                acc.w += xr[j] * w.w;
            }
        }
    }

    float4* pp = (float4*)&partial[((size_t)blockIdx.x * 16 + b) * 64 + q * 4];
    *pp = acc;
}

// ---------------------------------------------------------------------------
// Kernel 3: S[b,k,l] = sum_cg partial[(k*ncg+cg)][b][l]; then squash rows.
// One wave per (b,k) row; lane = l.
__global__ __launch_bounds__(256) void reduce_squash_kernel(
        const float* __restrict__ partial, float* __restrict__ out, int ncg) {
    int wave = threadIdx.x >> 6;
    int lane = threadIdx.x & 63;
    int row  = blockIdx.x * 4 + wave;      // [0,256) = b*16 + k
    int b = row >> 4, k = row & 15;
    float s = 0.f;
    for (int cg = 0; cg < ncg; ++cg)
        s += partial[((size_t)(k * ncg + cg) * 16 + b) * 64 + lane];
    float sq = s * s;
#pragma unroll
    for (int m = 32; m >= 1; m >>= 1) sq += __shfl_xor(sq, m);
    out[(size_t)row * 64 + lane] = (sq / (1.0f + sq)) * s / (sqrtf(sq) + 1e-5f);
}

// ---------------------------------------------------------------------------
extern "C" void kernel_launch(void* const* d_in, const int* in_sizes, int n_in,
                              void* d_out, int out_size, void* d_ws, size_t ws_size,
                              hipStream_t stream) {
    const float* x0  = (const float*)d_in[0];   // [16,512,8]
    const float* x1  = (const float*)d_in[1];   // [16,512,8]
    const float* W0  = (const float*)d_in[2];   // [16,512,8,64]
    const float* W1  = (const float*)d_in[3];   // [16,512,8,64]
    const float* bia = (const float*)d_in[4];   // [16,1024,1024]
    float* out = (float*)d_out;                 // [16,16,64]

    float* scale   = (float*)d_ws;              // 16*1024 floats
    float* partial = scale + 16 * 1024;         // 16*ncg*16*64 floats

    // pick chunks-per-block so partials fit in ws
    int cpb = 1;
    for (;;) {
        size_t need = ((size_t)16 * 1024 + (size_t)(64 / cpb) * 16 * 16 * 64) * sizeof(float);
        if (need <= ws_size || cpb == 64) break;
        cpb *= 4;
    }
    const int ncg = 64 / cpb;

    bsum_kernel<<<dim3(4096), dim3(256), 0, stream>>>(bia, scale);
    proj_kernel<<<dim3(16 * ncg), dim3(256), 0, stream>>>(x0, x1, W0, W1, scale,
                                                          partial, cpb, ncg);
    reduce_squash_kernel<<<dim3(64), dim3(256), 0, stream>>>(partial, out, ncg);
}

// Round 2
// 47.125 us; speedup vs baseline: 1.0692x; 1.0692x over previous
//
#include <hip/hip_runtime.h>

// Problem constants
//   B=16, N1=16, TOTAL_IN=1024 (two layers of 512 x dim 8), D1=64
// Key identity: softmax rows sum to 1, so
//   S[b,k,l] = sum_i U[b,k,i,l] * (1 + sum_z bias[k,i,z])
// => never materialize A [16,16,1024,1024] or the softmax.
// Fused: each block computes the bias rowsums for its own i-rows (disjoint
// across blocks -> bias still read exactly once), so bias + W streaming
// overlap in one kernel.

// ---------------------------------------------------------------------------
// Kernel 1: per block: fixed k, a group of 16-row i-chunks.
//   scale[i]   = 1 + sum_z bias[k,i,z]               (computed in-block)
//   acc[b][l] += sum_{i in chunk} scale[i] * sum_j x[b,i,j] * W[k,i,j,l]
// Thread t: b = t>>4 (16 b's), q = t&15 (l-quad, 4 l's) -> float4 acc.
// Writes deterministic partials: partial[blockIdx][b][l].
__global__ __launch_bounds__(256) void proj_kernel(
        const float* __restrict__ x0, const float* __restrict__ x1,
        const float* __restrict__ W0, const float* __restrict__ W1,
        const float* __restrict__ bias, float* __restrict__ partial,
        int cpb, int ncg) {
    __shared__ float xs[16 * 132];   // [i_local][b*8+j], stride 132 avoids bank conflicts
    __shared__ float ssum[16];       // per-i_local scale
    const int tid = threadIdx.x;
    const int k    = blockIdx.x / ncg;
    const int cgrp = blockIdx.x % ncg;
    const int b = tid >> 4;          // [0,16)
    const int q = tid & 15;          // l-quad [0,16)

    float4 acc = make_float4(0.f, 0.f, 0.f, 0.f);

    for (int cc = 0; cc < cpb; ++cc) {
        const int chunk = cgrp * cpb + cc;        // [0,64)
        const int layer = chunk >> 5;             // 0: first 512 caps, 1: second
        const int i0    = (chunk & 31) * 16;      // i within layer [0,512)
        const int ig0   = chunk * 16;             // global i [0,1024)
        const float* __restrict__ x = layer ? x1 : x0;
        const float* __restrict__ W = layer ? W1 : W0;

        __syncthreads();   // protect LDS reuse across chunks

        // ---- bias rowsum: row il (= tid>>4), 16 lanes p each sum 64 floats
        {
            const int il = tid >> 4, p = tid & 15;
            const float4* bp = (const float4*)(bias + ((size_t)(k * 1024 + ig0 + il)) * 1024);
            float s = 0.f;
#pragma unroll
            for (int it = 0; it < 16; ++it) {     // 16 lanes * 16 iters * 4 floats = 1024
                float4 v = bp[p + 16 * it];
                s += v.x + v.y + v.z + v.w;
            }
#pragma unroll
            for (int m = 8; m >= 1; m >>= 1) s += __shfl_xor(s, m);   // within 16-lane group
            if (p == 0) ssum[il] = 1.0f + s;
        }
        __syncthreads();

        // ---- stage xs[il][bb][j] = x[bb, i0+il, j] * scale[il]
        {
            const int il = tid & 15, bb = tid >> 4;
            const float s = ssum[il];
            const float4* xp = (const float4*)(x + (size_t)(bb * 512 + i0 + il) * 8);
            float4 a0 = xp[0], a1 = xp[1];
            float4* dst = (float4*)&xs[il * 132 + bb * 8];
            dst[0] = make_float4(a0.x * s, a0.y * s, a0.z * s, a0.w * s);
            dst[1] = make_float4(a1.x * s, a1.y * s, a1.z * s, a1.w * s);
        }
        __syncthreads();

        // ---- stream W, accumulate
        const float4* Wf4 = (const float4*)W;
        // float4 index of W[k][i0+il][j][q*4]: (k*512+i0+il)*128 + j*16 + q
        const size_t base = (size_t)(k * 512 + i0) * 128 + q;
        for (int il = 0; il < 16; ++il) {
            float xr[8];
            *(float4*)&xr[0] = *(const float4*)&xs[il * 132 + b * 8];
            *(float4*)&xr[4] = *(const float4*)&xs[il * 132 + b * 8 + 4];
            const float4* wp = Wf4 + base + (size_t)il * 128;
#pragma unroll
            for (int j = 0; j < 8; ++j) {
                float4 w = wp[j * 16];
                acc.x += xr[j] * w.x;
                acc.y += xr[j] * w.y;
                acc.z += xr[j] * w.z;
                acc.w += xr[j] * w.w;
            }
        }
    }

    float4* pp = (float4*)&partial[((size_t)blockIdx.x * 16 + b) * 64 + q * 4];
    *pp = acc;
}

// ---------------------------------------------------------------------------
// Kernel 2: S[b,k,l] = sum_cg partial[(k*ncg+cg)][b][l]; then squash rows.
// One wave per (b,k) row; lane = l.
__global__ __launch_bounds__(256) void reduce_squash_kernel(
        const float* __restrict__ partial, float* __restrict__ out, int ncg) {
    int wave = threadIdx.x >> 6;
    int lane = threadIdx.x & 63;
    int row  = blockIdx.x * 4 + wave;      // [0,256) = b*16 + k
    int b = row >> 4, k = row & 15;
    float s = 0.f;
    for (int cg = 0; cg < ncg; ++cg)
        s += partial[((size_t)(k * ncg + cg) * 16 + b) * 64 + lane];
    float sq = s * s;
#pragma unroll
    for (int m = 32; m >= 1; m >>= 1) sq += __shfl_xor(sq, m);
    out[(size_t)row * 64 + lane] = (sq / (1.0f + sq)) * s / (sqrtf(sq) + 1e-5f);
}

// ---------------------------------------------------------------------------
extern "C" void kernel_launch(void* const* d_in, const int* in_sizes, int n_in,
                              void* d_out, int out_size, void* d_ws, size_t ws_size,
                              hipStream_t stream) {
    const float* x0  = (const float*)d_in[0];   // [16,512,8]
    const float* x1  = (const float*)d_in[1];   // [16,512,8]
    const float* W0  = (const float*)d_in[2];   // [16,512,8,64]
    const float* W1  = (const float*)d_in[3];   // [16,512,8,64]
    const float* bia = (const float*)d_in[4];   // [16,1024,1024]
    float* out = (float*)d_out;                 // [16,16,64]

    float* partial = (float*)d_ws;              // 16*ncg*16*64 floats

    // pick chunks-per-block so partials fit in ws
    int cpb = 1;
    for (;;) {
        size_t need = (size_t)(64 / cpb) * 16 * 16 * 64 * sizeof(float);
        if (need <= ws_size || cpb == 64) break;
        cpb *= 4;
    }
    const int ncg = 64 / cpb;

    proj_kernel<<<dim3(16 * ncg), dim3(256), 0, stream>>>(x0, x1, W0, W1, bia,
                                                          partial, cpb, ncg);
    reduce_squash_kernel<<<dim3(64), dim3(256), 0, stream>>>(partial, out, ncg);
}

// Round 4
// 32.640 us; speedup vs baseline: 1.5437x; 1.4438x over previous
//
#include <hip/hip_runtime.h>

// B=16, N1=16, TOTAL_IN=1024 (two layers of 512 x dim 8), D1=64
// softmax rows sum to 1 =>  S[b,k,l] = sum_i (1 + rowsum_bias[k,i]) * U[b,k,i,l]
// One block per (k, 16-row i-chunk). Thread (g=i_local, q=l-quad):
//   - 8 fully-coalesced independent W float4 loads issued FIRST
//   - bias rowsum + x staging overlap the W latency
//   - per-thread acc over b (two halves of 8), i-reduction via wave shfl
//     (no LDS reuse, no extra barriers), per-wave partials to global.

__global__ __launch_bounds__(256) void proj_kernel(
        const float* __restrict__ x0, const float* __restrict__ x1,
        const float* __restrict__ W0, const float* __restrict__ W1,
        const float* __restrict__ bias, float* __restrict__ partial) {
    __shared__ float xs[16 * 132];   // [i_local][b*8+j], 528B row stride
    __shared__ float ssum[16];       // per-i_local scale
    const int tid = threadIdx.x;
    const int k     = blockIdx.x >> 6;     // [0,16)
    const int chunk = blockIdx.x & 63;     // [0,64)
    const int g  = tid >> 4;               // i_local [0,16)
    const int q  = tid & 15;               // l-quad  [0,16)
    const int w  = tid >> 6;               // wave    [0,4)
    const int gw = g & 3;                  // g within wave

    const int layer = chunk >> 5;
    const int i0    = (chunk & 31) * 16;   // i within layer
    const int ig0   = chunk * 16;          // global i
    const float* __restrict__ x = layer ? x1 : x0;
    const float* __restrict__ W = layer ? W1 : W0;

    // ---- 1. W loads first: thread (g,q) owns row i0+g, l-quad q, all j.
    // float4 index of W[k][i0+g][j][q*4] = (k*512+i0+g)*128 + j*16 + q
    const float4* Wf4 = (const float4*)W;
    const size_t wbase = (size_t)(k * 512 + i0 + g) * 128 + q;
    float4 wv[8];
#pragma unroll
    for (int j = 0; j < 8; ++j) wv[j] = Wf4[wbase + j * 16];

    // ---- 2. x loads (thread acts as bb=g, il=q for staging)
    const float4* xp = (const float4*)(x + (size_t)(g * 512 + i0 + q) * 8);
    float4 a0 = xp[0], a1 = xp[1];

    // ---- 3. bias rowsum for row ig0+g: 16 lanes q, 2 batches of 8 float4
    {
        const float4* bp = (const float4*)(bias + (size_t)(k * 1024 + ig0 + g) * 1024);
        float s0 = 0.f, s1 = 0.f, s2 = 0.f, s3 = 0.f;
#pragma unroll
        for (int batch = 0; batch < 2; ++batch) {
            float4 v[8];
#pragma unroll
            for (int it = 0; it < 8; ++it) v[it] = bp[q + 16 * (batch * 8 + it)];
#pragma unroll
            for (int it = 0; it < 8; it += 4) {
                s0 += v[it].x + v[it].y + v[it].z + v[it].w;
                s1 += v[it + 1].x + v[it + 1].y + v[it + 1].z + v[it + 1].w;
                s2 += v[it + 2].x + v[it + 2].y + v[it + 2].z + v[it + 2].w;
                s3 += v[it + 3].x + v[it + 3].y + v[it + 3].z + v[it + 3].w;
            }
        }
        float s = (s0 + s1) + (s2 + s3);
#pragma unroll
        for (int m = 8; m >= 1; m >>= 1) s += __shfl_xor(s, m);  // within 16-lane group
        if (q == 0) ssum[g] = 1.0f + s;
    }
    __syncthreads();

    // ---- 4. stage xs[il=q][bb=g][j] = x * scale
    {
        const float s = ssum[q];
        float4* dst = (float4*)&xs[q * 132 + g * 8];
        dst[0] = make_float4(a0.x * s, a0.y * s, a0.z * s, a0.w * s);
        dst[1] = make_float4(a1.x * s, a1.y * s, a1.z * s, a1.w * s);
    }
    __syncthreads();

    // ---- 5+6. FMA over b in two halves of 8; wave-reduce over gw; store.
#pragma unroll
    for (int half = 0; half < 2; ++half) {
        float4 acc[8];
#pragma unroll
        for (int bi = 0; bi < 8; ++bi) acc[bi] = make_float4(0.f, 0.f, 0.f, 0.f);
#pragma unroll
        for (int bi = 0; bi < 8; ++bi) {
            const int b = half * 8 + bi;
            float xr[8];
            *(float4*)&xr[0] = *(const float4*)&xs[g * 132 + b * 8];      // broadcast
            *(float4*)&xr[4] = *(const float4*)&xs[g * 132 + b * 8 + 4];
#pragma unroll
            for (int j = 0; j < 8; ++j) {
                acc[bi].x += xr[j] * wv[j].x;
                acc[bi].y += xr[j] * wv[j].y;
                acc[bi].z += xr[j] * wv[j].z;
                acc[bi].w += xr[j] * wv[j].w;
            }
        }
        // reduce over the 4 g-rows in this wave (lane bits 4,5)
#pragma unroll
        for (int bi = 0; bi < 8; ++bi) {
            acc[bi].x += __shfl_xor(acc[bi].x, 32); acc[bi].x += __shfl_xor(acc[bi].x, 16);
            acc[bi].y += __shfl_xor(acc[bi].y, 32); acc[bi].y += __shfl_xor(acc[bi].y, 16);
            acc[bi].z += __shfl_xor(acc[bi].z, 32); acc[bi].z += __shfl_xor(acc[bi].z, 16);
            acc[bi].w += __shfl_xor(acc[bi].w, 32); acc[bi].w += __shfl_xor(acc[bi].w, 16);
        }
        if (gw == 0) {
            // partial[(blockIdx*4 + w)][b][l],  l = q*4+e
#pragma unroll
            for (int bi = 0; bi < 8; ++bi) {
                const int b = half * 8 + bi;
                *(float4*)&partial[(((size_t)blockIdx.x * 4 + w) * 16 + b) * 64 + q * 4] = acc[bi];
            }
        }
    }
}

// ---------------------------------------------------------------------------
// One block per (b,k) row: S[b,k,l] = sum over 256 chunk-wave partials; squash.
__global__ __launch_bounds__(256) void reduce_squash_kernel(
        const float* __restrict__ partial, float* __restrict__ out) {
    __shared__ float red[4][64];
    const int row = blockIdx.x;            // [0,256) = b*16 + k
    const int b = row >> 4, k = row & 15;
    const int w = threadIdx.x >> 6, lane = threadIdx.x & 63;
    float s = 0.f;
    // t = chunk*4 + wave  in [0,256); linear index (k*256+t)*1024 + b*64 + lane
#pragma unroll 8
    for (int t = w; t < 256; t += 4)
        s += partial[((size_t)(k * 256 + t) * 16 + b) * 64 + lane];
    red[w][lane] = s;
    __syncthreads();
    if (w == 0) {
        float v = red[0][lane] + red[1][lane] + red[2][lane] + red[3][lane];
        float sq = v * v;
#pragma unroll
        for (int m = 32; m >= 1; m >>= 1) sq += __shfl_xor(sq, m);
        out[(size_t)row * 64 + lane] = (sq / (1.0f + sq)) * v / (sqrtf(sq) + 1e-5f);
    }
}

// ---------------------------------------------------------------------------
extern "C" void kernel_launch(void* const* d_in, const int* in_sizes, int n_in,
                              void* d_out, int out_size, void* d_ws, size_t ws_size,
                              hipStream_t stream) {
    const float* x0  = (const float*)d_in[0];   // [16,512,8]
    const float* x1  = (const float*)d_in[1];   // [16,512,8]
    const float* W0  = (const float*)d_in[2];   // [16,512,8,64]
    const float* W1  = (const float*)d_in[3];   // [16,512,8,64]
    const float* bia = (const float*)d_in[4];   // [16,1024,1024]
    float* out = (float*)d_out;                 // [16,16,64]

    float* partial = (float*)d_ws;              // 1024*4*16*64 floats = 16 MB

    proj_kernel<<<dim3(1024), dim3(256), 0, stream>>>(x0, x1, W0, W1, bia, partial);
    reduce_squash_kernel<<<dim3(256), dim3(256), 0, stream>>>(partial, out);
}

// Round 5
// 27.766 us; speedup vs baseline: 1.8147x; 1.1756x over previous
//
#include <hip/hip_runtime.h>

// B=16, N1=16, TOTAL_IN=1024 (two layers of 512 x dim 8), D1=64
// softmax rows sum to 1 =>  S[b,k,l] = sum_i (1 + rowsum_bias[k,i]) * U[b,k,i,l]
// One block per (k, 16-row i-chunk). Thread (g=i_local, q=l-quad):
//   - 8 fully-coalesced independent W float4 loads issued FIRST
//   - bias rowsum + x staging overlap the W latency
//   - per-thread acc over b (two halves of 8), i-reduction via wave shfl,
//     then cross-wave reduction via dedicated LDS buffer -> one 4KB
//     fully-reduced partial tile per block (4.2 MB total, was 16.8).

__global__ __launch_bounds__(256) void proj_kernel(
        const float* __restrict__ x0, const float* __restrict__ x1,
        const float* __restrict__ W0, const float* __restrict__ W1,
        const float* __restrict__ bias, float* __restrict__ partial) {
    __shared__ float xs[16 * 132];   // [i_local][b*8+j], 528B row stride
    __shared__ float ssum[16];       // per-i_local scale
    __shared__ float rbuf[4 * 8 * 64];  // [wave][bi][l] cross-wave reduction, 8KB
    const int tid = threadIdx.x;
    const int k     = blockIdx.x >> 6;     // [0,16)
    const int chunk = blockIdx.x & 63;     // [0,64)
    const int g  = tid >> 4;               // i_local [0,16)
    const int q  = tid & 15;               // l-quad  [0,16)
    const int w  = tid >> 6;               // wave    [0,4)
    const int gw = g & 3;                  // g within wave

    const int layer = chunk >> 5;
    const int i0    = (chunk & 31) * 16;   // i within layer
    const int ig0   = chunk * 16;          // global i
    const float* __restrict__ x = layer ? x1 : x0;
    const float* __restrict__ W = layer ? W1 : W0;

    // ---- 1. W loads first: thread (g,q) owns row i0+g, l-quad q, all j.
    // float4 index of W[k][i0+g][j][q*4] = (k*512+i0+g)*128 + j*16 + q
    const float4* Wf4 = (const float4*)W;
    const size_t wbase = (size_t)(k * 512 + i0 + g) * 128 + q;
    float4 wv[8];
#pragma unroll
    for (int j = 0; j < 8; ++j) wv[j] = Wf4[wbase + j * 16];

    // ---- 2. x loads (thread acts as bb=g, il=q for staging)
    const float4* xp = (const float4*)(x + (size_t)(g * 512 + i0 + q) * 8);
    float4 a0 = xp[0], a1 = xp[1];

    // ---- 3. bias rowsum for row ig0+g: 16 lanes q, 2 batches of 8 float4
    {
        const float4* bp = (const float4*)(bias + (size_t)(k * 1024 + ig0 + g) * 1024);
        float s0 = 0.f, s1 = 0.f, s2 = 0.f, s3 = 0.f;
#pragma unroll
        for (int batch = 0; batch < 2; ++batch) {
            float4 v[8];
#pragma unroll
            for (int it = 0; it < 8; ++it) v[it] = bp[q + 16 * (batch * 8 + it)];
#pragma unroll
            for (int it = 0; it < 8; it += 4) {
                s0 += v[it].x + v[it].y + v[it].z + v[it].w;
                s1 += v[it + 1].x + v[it + 1].y + v[it + 1].z + v[it + 1].w;
                s2 += v[it + 2].x + v[it + 2].y + v[it + 2].z + v[it + 2].w;
                s3 += v[it + 3].x + v[it + 3].y + v[it + 3].z + v[it + 3].w;
            }
        }
        float s = (s0 + s1) + (s2 + s3);
#pragma unroll
        for (int m = 8; m >= 1; m >>= 1) s += __shfl_xor(s, m);  // within 16-lane group
        if (q == 0) ssum[g] = 1.0f + s;
    }
    __syncthreads();

    // ---- 4. stage xs[il=q][bb=g][j] = x * scale
    {
        const float s = ssum[q];
        float4* dst = (float4*)&xs[q * 132 + g * 8];
        dst[0] = make_float4(a0.x * s, a0.y * s, a0.z * s, a0.w * s);
        dst[1] = make_float4(a1.x * s, a1.y * s, a1.z * s, a1.w * s);
    }
    __syncthreads();

    // ---- 5+6. FMA over b in two halves of 8; wave-shfl reduce over gw;
    //           cross-wave reduce via rbuf; store fully-reduced tile.
#pragma unroll
    for (int half = 0; half < 2; ++half) {
        float4 acc[8];
#pragma unroll
        for (int bi = 0; bi < 8; ++bi) acc[bi] = make_float4(0.f, 0.f, 0.f, 0.f);
#pragma unroll
        for (int bi = 0; bi < 8; ++bi) {
            const int b = half * 8 + bi;
            float xr[8];
            *(float4*)&xr[0] = *(const float4*)&xs[g * 132 + b * 8];      // broadcast
            *(float4*)&xr[4] = *(const float4*)&xs[g * 132 + b * 8 + 4];
#pragma unroll
            for (int j = 0; j < 8; ++j) {
                acc[bi].x += xr[j] * wv[j].x;
                acc[bi].y += xr[j] * wv[j].y;
                acc[bi].z += xr[j] * wv[j].z;
                acc[bi].w += xr[j] * wv[j].w;
            }
        }
        // reduce over the 4 g-rows in this wave (lane bits 4,5)
#pragma unroll
        for (int bi = 0; bi < 8; ++bi) {
            acc[bi].x += __shfl_xor(acc[bi].x, 32); acc[bi].x += __shfl_xor(acc[bi].x, 16);
            acc[bi].y += __shfl_xor(acc[bi].y, 32); acc[bi].y += __shfl_xor(acc[bi].y, 16);
            acc[bi].z += __shfl_xor(acc[bi].z, 32); acc[bi].z += __shfl_xor(acc[bi].z, 16);
            acc[bi].w += __shfl_xor(acc[bi].w, 32); acc[bi].w += __shfl_xor(acc[bi].w, 16);
        }
        if (gw == 0) {
            // each wave writes its own disjoint rbuf region
#pragma unroll
            for (int bi = 0; bi < 8; ++bi)
                *(float4*)&rbuf[(w * 8 + bi) * 64 + q * 4] = acc[bi];
        }
        __syncthreads();
        // cross-wave sum: thread -> (bi = tid>>5, l = tid&31 and +32)
        {
            const int bi = tid >> 5;        // [0,8)
            const int l  = tid & 31;
            float v0 = 0.f, v1 = 0.f;
#pragma unroll
            for (int ww = 0; ww < 4; ++ww) {
                v0 += rbuf[(ww * 8 + bi) * 64 + l];
                v1 += rbuf[(ww * 8 + bi) * 64 + l + 32];
            }
            const int b = half * 8 + bi;
            partial[(size_t)blockIdx.x * 1024 + b * 64 + l]      = v0;
            partial[(size_t)blockIdx.x * 1024 + b * 64 + l + 32] = v1;
        }
        __syncthreads();   // protect rbuf rewrite in next half
    }
}

// ---------------------------------------------------------------------------
// One block per (b,k) row: S[b,k,l] = sum over 64 chunk partials; squash.
__global__ __launch_bounds__(256) void reduce_squash_kernel(
        const float* __restrict__ partial, float* __restrict__ out) {
    __shared__ float red[4][64];
    const int row = blockIdx.x;            // [0,256) = b*16 + k
    const int b = row >> 4, k = row & 15;
    const int w = threadIdx.x >> 6, lane = threadIdx.x & 63;
    float s = 0.f;
#pragma unroll
    for (int cc = 0; cc < 16; ++cc) {
        const int c = w + cc * 4;          // wave-interleaved chunks [0,64)
        s += partial[((size_t)(k * 64 + c)) * 1024 + b * 64 + lane];
    }
    red[w][lane] = s;
    __syncthreads();
    if (w == 0) {
        float v = red[0][lane] + red[1][lane] + red[2][lane] + red[3][lane];
        float sq = v * v;
#pragma unroll
        for (int m = 32; m >= 1; m >>= 1) sq += __shfl_xor(sq, m);
        out[(size_t)row * 64 + lane] = (sq / (1.0f + sq)) * v / (sqrtf(sq) + 1e-5f);
    }
}

// ---------------------------------------------------------------------------
extern "C" void kernel_launch(void* const* d_in, const int* in_sizes, int n_in,
                              void* d_out, int out_size, void* d_ws, size_t ws_size,
                              hipStream_t stream) {
    const float* x0  = (const float*)d_in[0];   // [16,512,8]
    const float* x1  = (const float*)d_in[1];   // [16,512,8]
    const float* W0  = (const float*)d_in[2];   // [16,512,8,64]
    const float* W1  = (const float*)d_in[3];   // [16,512,8,64]
    const float* bia = (const float*)d_in[4];   // [16,1024,1024]
    float* out = (float*)d_out;                 // [16,16,64]

    float* partial = (float*)d_ws;              // 1024*1024 floats = 4 MB

    proj_kernel<<<dim3(1024), dim3(256), 0, stream>>>(x0, x1, W0, W1, bia, partial);
    reduce_squash_kernel<<<dim3(256), dim3(256), 0, stream>>>(partial, out);
}